// Round 5
// baseline (8105.315 us; speedup 1.0000x reference)
//
#include <hip/hip_runtime.h>
#include <stdint.h>

// ============================================================================
// CharNN: 2-layer GRU char LM (B=64, T=512, V=256, E=H=1024) on MI355X.
// Round 13: r11 base + counted-vmcnt pipelined mm48 + explicit pre-barrier
// drain. Evidence r10/r11/r12: chained-loads+any-barrier passes; batch-32+slow
// barrier passes; batch-32+fast barrier FAILS (absmax 1.42) -> suspected
// publication hole (compiler may skip vmcnt drain at __syncthreads for relaxed
// stores; slow barriers masked it) and/or 32-wide untracked-register batch.
//  * Change 1: ALL threads execute asm `s_waitcnt vmcnt(0)` + sched_barrier
//    immediately before barrier entry -> producer stores provably ACKed before
//    arrival store, independent of compiler choices.
//  * Change 2: mm48 = counted-vmcnt pipeline (AITER-style): issue 16 asm sc1
//    loads; 4 chunks of {s_waitcnt vmcnt(8|0); sched_barrier(0); refill 8;
//    sched_barrier(0); 8x3 MFMA}. <=24 untracked values live (~96 VGPR, budget
//    512 at 1 block/CU). Counts robust to compiler-interleaved cached loads
//    (oldest-first drain covers each chunk; tail chunk uses vmcnt(0)).
//  * Everything else (epilogues with post-mm48 atomic loads, sc1 stores,
//    aggregator/doorbell barrier) EXACTLY r11 (7954us, passing).
// ============================================================================

namespace {

constexpr int B = 64, T = 512, V = 256, H = 1024, G = 3072;  // G = 3*H
constexpr int NBLK = 192;

typedef _Float16 f16;
typedef unsigned long long u64;
typedef f16 f16x8 __attribute__((ext_vector_type(8)));
typedef f16 f16x4 __attribute__((ext_vector_type(4)));
typedef float f32x4 __attribute__((ext_vector_type(4)));

#define MFMA16(av, bv, acc) __builtin_amdgcn_mfma_f32_16x16x32_f16(av, bv, acc, 0, 0, 0)

// ---- relaxed agent-scope (MALL-coherent) access helpers --------------------
__device__ __forceinline__ float aload2(const f16* p) {
  unsigned short s = __hip_atomic_load(
      reinterpret_cast<const unsigned short*>(p), __ATOMIC_RELAXED,
      __HIP_MEMORY_SCOPE_AGENT);
  union { unsigned short s; f16 f; } u;
  u.s = s;
  return (float)u.f;
}
__device__ __forceinline__ void astore2(f16* p, float v) {
  union { f16 f; unsigned short s; } u;
  u.f = (f16)v;
  __hip_atomic_store(reinterpret_cast<unsigned short*>(p), u.s,
                     __ATOMIC_RELAXED, __HIP_MEMORY_SCOPE_AGENT);
}
__device__ __forceinline__ float aloadf(const float* p) {
  return __hip_atomic_load(p, __ATOMIC_RELAXED, __HIP_MEMORY_SCOPE_AGENT);
}
__device__ __forceinline__ void astoref(float* p, float v) {
  __hip_atomic_store(p, v, __ATOMIC_RELAXED, __HIP_MEMORY_SCOPE_AGENT);
}
__device__ __forceinline__ void astorei(int* p, int v) {
  __hip_atomic_store(p, v, __ATOMIC_RELAXED, __HIP_MEMORY_SCOPE_AGENT);
}

// ---- pipelinable MALL load (plain asm, sc1). NOT compiler-tracked: consumer
// must s_waitcnt manually (mm48's counted waits). --------------------------
__device__ __forceinline__ f16x8 bload16(const f16* p) {
  f16x8 v;
  asm volatile("global_load_dwordx4 %0, %1, off sc1" : "=v"(v) : "v"(p));
  return v;
}

// ---- aggregator poll: 3 independent MALL loads, one wait -------------------
__device__ __forceinline__ void poll3(const int* p0, const int* p1,
                                      const int* p2, int& a0, int& a1,
                                      int& a2) {
  asm volatile(
      "global_load_dword %0, %3, off sc1\n\t"
      "global_load_dword %1, %4, off sc1\n\t"
      "global_load_dword %2, %5, off sc1\n\t"
      "s_waitcnt vmcnt(0)"
      : "=&v"(a0), "=&v"(a1), "=&v"(a2)
      : "v"(p0), "v"(p1), "v"(p2)
      : "memory");
}

// ---- 48-row x K=1024 MFMA block, counted-vmcnt pipeline --------------------
// Issue 16 loads; per 8-chunk: wait oldest-8 done, refill 8, 24 MFMAs.
// Robust to foreign (compiler-tracked) VMEM ops interleaving: vmcnt drains
// oldest-first, so each chunk's ring loads are provably complete; the tail
// chunk waits vmcnt(0).
__device__ __forceinline__ void mm48(const f16* a, const f16* wp, f32x4& aR,
                                     f32x4& aZ, f32x4& aN) {
  f16x8 hv[32];
#pragma unroll
  for (int q = 0; q < 16; ++q) hv[q] = bload16(a + q * 2048);
#pragma unroll
  for (int c = 0; c < 4; ++c) {
    if (c < 3) {
      asm volatile("s_waitcnt vmcnt(8)" ::: "memory");
    } else {
      asm volatile("s_waitcnt vmcnt(0)" ::: "memory");
    }
    __builtin_amdgcn_sched_barrier(0);  // rule #18: pin MFMAs below the wait
    if (c < 2) {
#pragma unroll
      for (int q = 0; q < 8; ++q)
        hv[16 + c * 8 + q] = bload16(a + (16 + c * 8 + q) * 2048);
    }
    __builtin_amdgcn_sched_barrier(0);
#pragma unroll
    for (int k = 0; k < 8; ++k) {
      const int k0 = c * 8 + k;
      const f16* w = wp + k0 * 1728;
      aR = MFMA16(hv[k0], *reinterpret_cast<const f16x8*>(w), aR);
      aZ = MFMA16(hv[k0], *reinterpret_cast<const f16x8*>(w + 576), aZ);
      aN = MFMA16(hv[k0], *reinterpret_cast<const f16x8*>(w + 1152), aN);
    }
  }
}

// ---- fp32 -> fp16 convert (x4 vectorized) ----------------------------------
__global__ void to_f16_4(const float* __restrict__ src, f16* __restrict__ dst,
                         int n4) {
  int i = blockIdx.x * 256 + threadIdx.x;
  if (i >= n4) return;
  float4 v = reinterpret_cast<const float4*>(src)[i];
  f16x4 o = {(f16)v.x, (f16)v.y, (f16)v.z, (f16)v.w};
  reinterpret_cast<f16x4*>(dst)[i] = o;
}

// ---- pack the 3 role weight images -----------------------------------------
// dst[which][bi][k0<32][row<48][kk<32] f16, dense. row = g*16 + jrow,
// j = bi*16 + jrow. which: 0 = W_hh[0], 1 = W_ih[1], 2 = W_hh[1].
__global__ void pack_w(const float* __restrict__ Whh,
                       const float* __restrict__ Wih, f16* __restrict__ dst) {
  const int id = blockIdx.x * 256 + threadIdx.x;  // 1,179,648 vec8 elems
  const int kkq = id & 3;
  const int rr = id >> 2;
  const int row = rr % 48;
  const int rest = rr / 48;
  const int k0 = rest & 31, bi = (rest >> 5) & 63, which = rest >> 11;
  const int g = row >> 4, jrow = row & 15;
  const float* base = (which == 0) ? Whh
                    : (which == 1) ? (Wih + (size_t)G * H)
                                   : (Whh + (size_t)G * H);
  const float* src =
      base + ((size_t)(g * H + bi * 16 + jrow)) * H + k0 * 32 + kkq * 8;
  float4 a = *reinterpret_cast<const float4*>(src);
  float4 b = *reinterpret_cast<const float4*>(src + 4);
  f16x8 o = {(f16)a.x, (f16)a.y, (f16)a.z, (f16)a.w,
             (f16)b.x, (f16)b.y, (f16)b.z, (f16)b.w};
  *reinterpret_cast<f16x8*>(dst + (size_t)id * 8) = o;
}

// ---- pack h0 into tiled layout [k0][b][kk] fp16 + zero barrier arrays ------
__global__ void pack_h0f(const float* __restrict__ h0, f16* __restrict__ h1,
                         f16* __restrict__ h2, int* __restrict__ bar) {
  if (blockIdx.x == 0 && threadIdx.x < NBLK) {
    bar[threadIdx.x * 16] = 0;         // arrive slots
    bar[4096 + threadIdx.x * 16] = 0;  // doorbell slots
  }
  const int id = blockIdx.x * 256 + threadIdx.x;  // 131072
  const int layer = id >> 16, b = (id >> 10) & 63, j = id & 1023;
  const size_t a = ((size_t)(j >> 5) * 64 + b) * 32 + (j & 31);
  const f16 v = (f16)h0[id];
  if (layer == 0) h1[a] = v; else h2[a] = v;
}

// ---- fp16 GEMM: C[M,N] = A @ B[N,K]^T + bias -------------------------------
// MODE 0: A row-major [M,K], C fp32 [M,N].
// MODE 2: logits. A is y2 in tiled per-t slabs ([t][k0][b][kk], 65536/t);
//         bm indexes t; write out[(b*(T-1)+t)*V + n] for t < T-1.
template <int MODE>
__global__ __launch_bounds__(256) void gemm_f16(
    const f16* __restrict__ A, const f16* __restrict__ Bm,
    const float* __restrict__ bias, float* __restrict__ C, int M, int N,
    int K) {
  __shared__ __align__(16) f16 As[64][48], Bs[64][48];

  const int tid = threadIdx.x;
  const int lane = tid & 63, wv = tid >> 6;
  const int bm = blockIdx.y, bn = blockIdx.x;
  const int srow = tid >> 2, sseg = (tid & 3) * 8;

  const f16* pA = (MODE == 2)
                      ? (A + (size_t)bm * 65536 + srow * 32 + sseg)
                      : (A + (size_t)(bm * 64 + srow) * K + sseg);
  const f16* pB = Bm + (size_t)(bn * 64 + srow) * K + sseg;

  f32x4 acc[4];
  const f32x4 zero = {0.f, 0.f, 0.f, 0.f};
#pragma unroll
  for (int nt = 0; nt < 4; ++nt) acc[nt] = zero;

  const int ar = wv * 16 + (lane & 15);
  const int kk = (lane >> 4) * 8;

  const int niter = K / 32;
  for (int ki = 0; ki < niter; ++ki) {
    int4 va = (MODE == 2) ? *reinterpret_cast<const int4*>(pA + ki * 2048)
                          : *reinterpret_cast<const int4*>(pA + ki * 32);
    int4 vb = *reinterpret_cast<const int4*>(pB + ki * 32);
    __syncthreads();
    *reinterpret_cast<int4*>(&As[srow][sseg]) = va;
    *reinterpret_cast<int4*>(&Bs[srow][sseg]) = vb;
    __syncthreads();

    f16x8 av = *reinterpret_cast<const f16x8*>(&As[ar][kk]);
#pragma unroll
    for (int nt = 0; nt < 4; ++nt) {
      f16x8 bv = *reinterpret_cast<const f16x8*>(&Bs[nt * 16 + (lane & 15)][kk]);
      acc[nt] = MFMA16(av, bv, acc[nt]);
    }
  }

  const int rbase = wv * 16 + (lane >> 4) * 4;
  const int cl = lane & 15;
#pragma unroll
  for (int nt = 0; nt < 4; ++nt) {
    const int n = bn * 64 + nt * 16 + cl;
    const float bv = bias[n];
#pragma unroll
    for (int r = 0; r < 4; ++r) {
      const int m = bm * 64 + rbase + r;
      const float v = acc[nt][r] + bv;
      if (MODE == 0) {
        C[(size_t)m * N + n] = v;
      } else {
        const int t = m >> 6, bb = m & 63;
        if (t < T - 1) C[((size_t)(bb * (T - 1) + t)) * V + n] = v;
      }
    }
  }
}

// ---- persistent 3-role GRU pipeline ----------------------------------------
// 192 blocks x 256 threads (cooperative). role = bx>>6, jb = bx&63.
// Interval i: L1 computes h1[t=i] (i<512); GX computes gx2[t=i-1] (1<=i<=512);
// L2 computes h2[t=i-2] + y2 row (2<=i<=513).
// Barrier: explicit per-wave vmcnt(0) drain -> __syncthreads -> arrive-store
// -> single-aggregator detect -> doorbell release.
// bar layout (ints): arrive = bar[bx*16]; door = bar[4096 + bx*16].
__global__ __launch_bounds__(256, 1) void gru_persist(
    const f16* __restrict__ pW, const float* __restrict__ G0,
    const int* __restrict__ X, const float* __restrict__ b_hh,
    const float* __restrict__ b_ih, f16* __restrict__ h1a,
    f16* __restrict__ h1b, f16* __restrict__ h2a, f16* __restrict__ h2b,
    float* __restrict__ gx2, f16* __restrict__ y2, int* __restrict__ bar) {
  __shared__ __align__(16) f16 Wt[55296];  // [k0<32][row<48][kk padded to 36]

  const int tid = threadIdx.x, bx = blockIdx.x;
  const int lane = tid & 63, wv = tid >> 6;
  const int l15 = lane & 15, kq = lane >> 4;
  const int role = bx >> 6, jb = bx & 63;

  int* arrive = bar;
  int* door = bar + 4096;

  // ---- stage this block's 96KB W image (dense global -> padded LDS) ----
  {
    const int2* src = reinterpret_cast<const int2*>(pW + (size_t)bx * 49152);
#pragma unroll
    for (int q = 0; q < 48; ++q) {
      const int flat = q * 256 + tid;   // 12288 int2
      const int k0r = flat >> 3, seg = flat & 7;
      *reinterpret_cast<int2*>(&Wt[k0r * 36 + seg * 4]) = src[flat];
    }
  }
  __syncthreads();

  const int j = jb * 16 + l15;
  float br_ = 0.f, bz_ = 0.f, bn_ = 0.f, bxr_ = 0.f, bxz_ = 0.f, bxn_ = 0.f;
  if (role == 0) {
    br_ = b_hh[j]; bz_ = b_hh[H + j]; bn_ = b_hh[2 * H + j];
  } else if (role == 2) {
    br_ = b_hh[G + j]; bz_ = b_hh[G + H + j]; bn_ = b_hh[G + 2 * H + j];
    bxr_ = b_ih[G + j]; bxz_ = b_ih[G + H + j]; bxn_ = b_ih[G + 2 * H + j];
  }

  f16* h1buf[2] = {h1a, h1b};
  f16* h2buf[2] = {h2a, h2b};
  const int aoff = (wv * 16 + l15) * 32 + kq * 8;
  const f16* wp = Wt + l15 * 36 + kq * 8;  // + k0*1728 + g*576
  const int bB = wv * 16 + kq * 4;
  const size_t hoff = (size_t)(j >> 5) * 2048 + (j & 31);

  for (int i = 0; i <= T + 1; ++i) {
    if (role == 0) {
      if (i < T) {  // ---- L1: h1[t=i] ----
        const f16* hin = h1buf[i & 1];
        f16* hout = h1buf[(i + 1) & 1];
        f32x4 aR = {0, 0, 0, 0}, aZ = {0, 0, 0, 0}, aN = {0, 0, 0, 0};
        mm48(hin + aoff, wp, aR, aZ, aN);
#pragma unroll
        for (int r = 0; r < 4; ++r) {
          const int b = bB + r;
          const float* gx = G0 + (size_t)X[b * T + i] * G;
          const float xr = gx[j], xz = gx[H + j], xn = gx[2 * H + j];
          const size_t ha = hoff + (size_t)b * 32;
          const float hp = aload2(hin + ha);
          const float rg = 1.f / (1.f + __expf(-(xr + aR[r] + br_)));
          const float zg = 1.f / (1.f + __expf(-(xz + aZ[r] + bz_)));
          const float ng = tanhf(xn + rg * (aN[r] + bn_));
          astore2(hout + ha, (1.f - zg) * ng + zg * hp);
        }
      }
    } else if (role == 1) {
      if (i >= 1 && i <= T) {  // ---- GX: gx2[t=i-1] = y1[t] @ W_ih1^T ----
        const int t = i - 1;
        f32x4 aR = {0, 0, 0, 0}, aZ = {0, 0, 0, 0}, aN = {0, 0, 0, 0};
        mm48(h1buf[i & 1] + aoff, wp, aR, aZ, aN);  // y1[t] = h1 after step t
        float* gdst = gx2 + ((size_t)(t & 1) * 64 + jb) * 3072;
#pragma unroll
        for (int r = 0; r < 4; ++r) {
          const int b = bB + r;
          astoref(gdst + b * 16 + l15, aR[r]);
          astoref(gdst + 1024 + b * 16 + l15, aZ[r]);
          astoref(gdst + 2048 + b * 16 + l15, aN[r]);
        }
      }
    } else {
      if (i >= 2) {  // ---- L2: h2[t=i-2] + y2 ----
        const int t = i - 2;
        const f16* hin = h2buf[i & 1];
        f16* hout = h2buf[(i + 1) & 1];
        const float* gsrc = gx2 + ((size_t)(t & 1) * 64 + jb) * 3072;
        f32x4 aR = {0, 0, 0, 0}, aZ = {0, 0, 0, 0}, aN = {0, 0, 0, 0};
        mm48(hin + aoff, wp, aR, aZ, aN);
#pragma unroll
        for (int r = 0; r < 4; ++r) {
          const int b = bB + r;
          const float xr = aloadf(gsrc + b * 16 + l15);
          const float xz = aloadf(gsrc + 1024 + b * 16 + l15);
          const float xn = aloadf(gsrc + 2048 + b * 16 + l15);
          const size_t ha = hoff + (size_t)b * 32;
          const float hp = aload2(hin + ha);
          const float rg = 1.f / (1.f + __expf(-(xr + bxr_ + aR[r] + br_)));
          const float zg = 1.f / (1.f + __expf(-(xz + bxz_ + aZ[r] + bz_)));
          const float ng = tanhf(xn + bxn_ + rg * (aN[r] + bn_));
          const float hv = (1.f - zg) * ng + zg * hp;
          astore2(hout + ha, hv);
          y2[(size_t)t * 65536 + ha] = (f16)hv;  // plain (read post-kernel)
        }
      }
    }

    // ---- explicit publication drain + contention-free barrier ----
    // EVERY thread drains vmcnt itself (compiler may legally skip a vmcnt
    // drain at __syncthreads for relaxed stores -> publication hole when the
    // barrier is fast). Then: arrive-store / aggregator detect / doorbell.
    asm volatile("s_waitcnt vmcnt(0)" ::: "memory");
    __builtin_amdgcn_sched_barrier(0);
    __syncthreads();
    const int ph = i + 1;
    if (tid == 0) astorei(&arrive[bx * 16], ph);
    if (bx == 0) {
      if (tid < 64) {  // aggregator wave
        int a0, a1, a2;
        for (;;) {
          poll3(&arrive[tid * 16], &arrive[(64 + tid) * 16],
                &arrive[(128 + tid) * 16], a0, a1, a2);
          if (__all(a0 >= ph && a1 >= ph && a2 >= ph)) break;
          __builtin_amdgcn_s_sleep(1);
        }
        astorei(&door[tid * 16], ph);
        astorei(&door[(64 + tid) * 16], ph);
        astorei(&door[(128 + tid) * 16], ph);
      }
    } else if (tid == 0) {
      while (__hip_atomic_load(&door[bx * 16], __ATOMIC_RELAXED,
                               __HIP_MEMORY_SCOPE_AGENT) < ph) {
        __builtin_amdgcn_s_sleep(1);
      }
    }
    __syncthreads();
    asm volatile("" ::: "memory");
  }
}

}  // namespace

// ============================================================================
extern "C" void kernel_launch(void* const* d_in, const int* in_sizes, int n_in,
                              void* d_out, int out_size, void* d_ws,
                              size_t ws_size, hipStream_t stream) {
  const int* X = (const int*)d_in[0];
  const float* h0 = (const float*)d_in[1];
  const float* emb = (const float*)d_in[2];
  const float* W_ih = (const float*)d_in[3];
  const float* W_hh = (const float*)d_in[4];
  const float* b_ih = (const float*)d_in[5];
  const float* b_hh = (const float*)d_in[6];
  const float* W_out = (const float*)d_in[7];
  const float* b_out = (const float*)d_in[8];
  float* out = (float*)d_out;
  (void)in_sizes; (void)n_in; (void)out_size; (void)ws_size;

  // ---- workspace (~94 MB) ----
  char* p = (char*)d_ws;
  auto alloc = [&](size_t bytes) {
    char* q = p;
    p += (bytes + 255) & ~(size_t)255;
    return q;
  };
  f16* pW = (f16*)alloc((size_t)3 * 64 * 49152 * 2);  // 18 MB (3 role images)
  float* G0 = (float*)alloc((size_t)V * G * 4);       // 3 MB
  f16* emb16 = (f16*)alloc((size_t)V * H * 2);
  f16* wih0_16 = (f16*)alloc((size_t)G * H * 2);      // 6 MB
  f16* wout16 = (f16*)alloc((size_t)V * H * 2);
  f16* h1a = (f16*)alloc((size_t)B * H * 2);
  f16* h1b = (f16*)alloc((size_t)B * H * 2);
  f16* h2a = (f16*)alloc((size_t)B * H * 2);
  f16* h2b = (f16*)alloc((size_t)B * H * 2);
  float* gx2 = (float*)alloc((size_t)2 * 64 * 3072 * 4);  // 1.5 MB
  f16* y2 = (f16*)alloc((size_t)T * B * H * 2);           // 64 MB
  int* bar = (int*)alloc(32768);  // arrive[192*16] + door at +4096 ints
  // arrive/door slots zeroed by pack_h0f (kernel-end L2 flush publishes).

  // ---- one-time converts / packs / G0 ----
  to_f16_4<<<(V * H / 4 + 255) / 256, 256, 0, stream>>>(emb, emb16, V * H / 4);
  to_f16_4<<<(G * H / 4 + 255) / 256, 256, 0, stream>>>(W_ih, wih0_16,
                                                        G * H / 4);
  to_f16_4<<<(V * H / 4 + 255) / 256, 256, 0, stream>>>(W_out, wout16,
                                                        V * H / 4);
  pack_w<<<4608, 256, 0, stream>>>(W_hh, W_ih, pW);
  pack_h0f<<<512, 256, 0, stream>>>(h0, h1a, h2a, bar);
  gemm_f16<0><<<dim3(G / 64, V / 64), 256, 0, stream>>>(emb16, wih0_16, b_ih,
                                                        G0, V, G, H);

  // ---- persistent 3-role pipeline (cooperative: guarantees co-residency) ----
  {
    const f16* a0 = pW; const float* a1 = G0; const int* a2 = X;
    const float* a3 = b_hh; const float* a4 = b_ih;
    f16* a5 = h1a; f16* a6 = h1b; f16* a7 = h2a; f16* a8 = h2b;
    float* a9 = gx2; f16* a10 = y2; int* a11 = bar;
    void* args[] = {&a0, &a1, &a2, &a3, &a4, &a5, &a6,
                    &a7, &a8, &a9, &a10, &a11};
    hipLaunchCooperativeKernel((const void*)gru_persist, dim3(NBLK), dim3(256),
                               args, 0, stream);
  }

  // ---- logits = y2 @ W_out^T + b_out (drop t = T-1 rows) ----
  gemm_f16<2><<<dim3(V / 64, T), 256, 0, stream>>>(y2, wout16, b_out, out,
                                                   T * B, V, H);
}

// Round 6
// 7419.270 us; speedup vs baseline: 1.0925x; 1.0925x over previous
//
#include <hip/hip_runtime.h>
#include <stdint.h>

// ============================================================================
// CharNN: 2-layer GRU char LM (B=64, T=512, V=256, E=H=1024) on MI355X.
// Round 14: kill the MALL broadcast volume via write-once rotating buffers.
//  * Evidence r8-r13: ALL load-issue strategies (chained atomic / 32-deep asm
//    batch / counted-vmcnt pipeline) give the same ~15us interval with the
//    r11 barrier -> not latency-bound. Invariant: 192 blocks x 128KB sc1
//    (L2-bypass) h-reads = 24.6MB/interval served entirely by the MALL (no L2
//    dedup). At ~1.6-2TB/s uncached service that burst IS the ~13us floor.
//  * Fix: rotate h buffer ADDRESSES so every interval's h lives at fresh,
//    never-before-touched addresses (h1: depth-128 ring; h2: full 513-slab
//    ring which IS y2 -> separate y2 store deleted). Producers keep sc1
//    stores (no dirty L2 line ever exists); consumers use PLAIN CACHED loads.
//    Write-once addressing makes staleness impossible without any fence:
//    an address is written (sc1, drained before the barrier) exactly once,
//    before any consumer touches it; GPU L2/L1 have no prefetcher. Per XCD
//    the first toucher fills L2 from MALL, ~23 other blocks hit L2:
//    MALL read volume 24.6MB -> ~2MB per interval.
//  * gx2 stays sc1 both ways (reuse distance 2 -> must bypass L2; small).
//  * mm48 = r9's proven plain-load ring-8 (compiler-pipelined, 132 VGPR).
//  * Barrier = r11 aggregator/doorbell + r13 explicit pre-barrier vmcnt drain.
// ============================================================================

namespace {

constexpr int B = 64, T = 512, V = 256, H = 1024, G = 3072;  // G = 3*H
constexpr int NBLK = 192;
constexpr int SLAB = 65536;   // f16 elems per h slab (64 b x 1024 j)
constexpr int R1MASK = 127;   // h1 ring depth 128

typedef _Float16 f16;
typedef unsigned long long u64;
typedef f16 f16x8 __attribute__((ext_vector_type(8)));
typedef f16 f16x4 __attribute__((ext_vector_type(4)));
typedef float f32x4 __attribute__((ext_vector_type(4)));

#define MFMA16(av, bv, acc) __builtin_amdgcn_mfma_f32_16x16x32_f16(av, bv, acc, 0, 0, 0)

// ---- plain cached loads (safe: write-once rotating addresses) --------------
__device__ __forceinline__ f16x8 lload16(const f16* p) {
  return *reinterpret_cast<const f16x8*>(p);
}
__device__ __forceinline__ float lload2(const f16* p) { return (float)*p; }

// ---- relaxed agent-scope (MALL, L2-bypass) access helpers ------------------
__device__ __forceinline__ void astore2(f16* p, float v) {
  union { f16 f; unsigned short s; } u;
  u.f = (f16)v;
  __hip_atomic_store(reinterpret_cast<unsigned short*>(p), u.s,
                     __ATOMIC_RELAXED, __HIP_MEMORY_SCOPE_AGENT);
}
__device__ __forceinline__ float aloadf(const float* p) {
  return __hip_atomic_load(p, __ATOMIC_RELAXED, __HIP_MEMORY_SCOPE_AGENT);
}
__device__ __forceinline__ void astoref(float* p, float v) {
  __hip_atomic_store(p, v, __ATOMIC_RELAXED, __HIP_MEMORY_SCOPE_AGENT);
}
__device__ __forceinline__ void astorei(int* p, int v) {
  __hip_atomic_store(p, v, __ATOMIC_RELAXED, __HIP_MEMORY_SCOPE_AGENT);
}

// ---- aggregator poll: 3 independent MALL loads, one wait -------------------
__device__ __forceinline__ void poll3(const int* p0, const int* p1,
                                      const int* p2, int& a0, int& a1,
                                      int& a2) {
  asm volatile(
      "global_load_dword %0, %3, off sc1\n\t"
      "global_load_dword %1, %4, off sc1\n\t"
      "global_load_dword %2, %5, off sc1\n\t"
      "s_waitcnt vmcnt(0)"
      : "=&v"(a0), "=&v"(a1), "=&v"(a2)
      : "v"(p0), "v"(p1), "v"(p2)
      : "memory");
}

// ---- 48-row x K=1024 MFMA block, plain cached loads, ring-8 prefetch -------
__device__ __forceinline__ void mm48(const f16* a, const f16* wp, f32x4& aR,
                                     f32x4& aZ, f32x4& aN) {
  f16x8 ring[8];
#pragma unroll
  for (int q = 0; q < 8; ++q) ring[q] = lload16(a + q * 2048);
#pragma unroll
  for (int k0 = 0; k0 < 32; ++k0) {
    f16x8 av = ring[k0 & 7];
    if (k0 + 8 < 32) ring[k0 & 7] = lload16(a + (k0 + 8) * 2048);
    const f16* w = wp + k0 * 1728;
    aR = MFMA16(av, *reinterpret_cast<const f16x8*>(w), aR);
    aZ = MFMA16(av, *reinterpret_cast<const f16x8*>(w + 576), aZ);
    aN = MFMA16(av, *reinterpret_cast<const f16x8*>(w + 1152), aN);
  }
}

// ---- fp32 -> fp16 convert (x4 vectorized) ----------------------------------
__global__ void to_f16_4(const float* __restrict__ src, f16* __restrict__ dst,
                         int n4) {
  int i = blockIdx.x * 256 + threadIdx.x;
  if (i >= n4) return;
  float4 v = reinterpret_cast<const float4*>(src)[i];
  f16x4 o = {(f16)v.x, (f16)v.y, (f16)v.z, (f16)v.w};
  reinterpret_cast<f16x4*>(dst)[i] = o;
}

// ---- pack the 3 role weight images -----------------------------------------
// dst[which][bi][k0<32][row<48][kk<32] f16, dense. row = g*16 + jrow,
// j = bi*16 + jrow. which: 0 = W_hh[0], 1 = W_ih[1], 2 = W_hh[1].
__global__ void pack_w(const float* __restrict__ Whh,
                       const float* __restrict__ Wih, f16* __restrict__ dst) {
  const int id = blockIdx.x * 256 + threadIdx.x;  // 1,179,648 vec8 elems
  const int kkq = id & 3;
  const int rr = id >> 2;
  const int row = rr % 48;
  const int rest = rr / 48;
  const int k0 = rest & 31, bi = (rest >> 5) & 63, which = rest >> 11;
  const int g = row >> 4, jrow = row & 15;
  const float* base = (which == 0) ? Whh
                    : (which == 1) ? (Wih + (size_t)G * H)
                                   : (Whh + (size_t)G * H);
  const float* src =
      base + ((size_t)(g * H + bi * 16 + jrow)) * H + k0 * 32 + kkq * 8;
  float4 a = *reinterpret_cast<const float4*>(src);
  float4 b = *reinterpret_cast<const float4*>(src + 4);
  f16x8 o = {(f16)a.x, (f16)a.y, (f16)a.z, (f16)a.w,
             (f16)b.x, (f16)b.y, (f16)b.z, (f16)b.w};
  *reinterpret_cast<f16x8*>(dst + (size_t)id * 8) = o;
}

// ---- pack h0 into ring slab 0 of each layer + zero barrier arrays ----------
__global__ void pack_h0f(const float* __restrict__ h0, f16* __restrict__ h1r,
                         f16* __restrict__ h2r, int* __restrict__ bar) {
  if (blockIdx.x == 0 && threadIdx.x < NBLK) {
    bar[threadIdx.x * 16] = 0;         // arrive slots
    bar[4096 + threadIdx.x * 16] = 0;  // doorbell slots
  }
  const int id = blockIdx.x * 256 + threadIdx.x;  // 131072
  const int layer = id >> 16, b = (id >> 10) & 63, j = id & 1023;
  const size_t a = ((size_t)(j >> 5) * 64 + b) * 32 + (j & 31);
  const f16 v = (f16)h0[id];
  if (layer == 0) h1r[a] = v; else h2r[a] = v;
}

// ---- fp16 GEMM: C[M,N] = A @ B[N,K]^T + bias -------------------------------
// MODE 0: A row-major [M,K], C fp32 [M,N].
// MODE 2: logits. A = h2ring + SLAB (slab t+1 = y2[t], per-t slabs of 65536);
//         bm indexes t; write out[(b*(T-1)+t)*V + n] for t < T-1.
template <int MODE>
__global__ __launch_bounds__(256) void gemm_f16(
    const f16* __restrict__ A, const f16* __restrict__ Bm,
    const float* __restrict__ bias, float* __restrict__ C, int M, int N,
    int K) {
  __shared__ __align__(16) f16 As[64][48], Bs[64][48];

  const int tid = threadIdx.x;
  const int lane = tid & 63, wv = tid >> 6;
  const int bm = blockIdx.y, bn = blockIdx.x;
  const int srow = tid >> 2, sseg = (tid & 3) * 8;

  const f16* pA = (MODE == 2)
                      ? (A + (size_t)bm * 65536 + srow * 32 + sseg)
                      : (A + (size_t)(bm * 64 + srow) * K + sseg);
  const f16* pB = Bm + (size_t)(bn * 64 + srow) * K + sseg;

  f32x4 acc[4];
  const f32x4 zero = {0.f, 0.f, 0.f, 0.f};
#pragma unroll
  for (int nt = 0; nt < 4; ++nt) acc[nt] = zero;

  const int ar = wv * 16 + (lane & 15);
  const int kk = (lane >> 4) * 8;

  const int niter = K / 32;
  for (int ki = 0; ki < niter; ++ki) {
    int4 va = (MODE == 2) ? *reinterpret_cast<const int4*>(pA + ki * 2048)
                          : *reinterpret_cast<const int4*>(pA + ki * 32);
    int4 vb = *reinterpret_cast<const int4*>(pB + ki * 32);
    __syncthreads();
    *reinterpret_cast<int4*>(&As[srow][sseg]) = va;
    *reinterpret_cast<int4*>(&Bs[srow][sseg]) = vb;
    __syncthreads();

    f16x8 av = *reinterpret_cast<const f16x8*>(&As[ar][kk]);
#pragma unroll
    for (int nt = 0; nt < 4; ++nt) {
      f16x8 bv = *reinterpret_cast<const f16x8*>(&Bs[nt * 16 + (lane & 15)][kk]);
      acc[nt] = MFMA16(av, bv, acc[nt]);
    }
  }

  const int rbase = wv * 16 + (lane >> 4) * 4;
  const int cl = lane & 15;
#pragma unroll
  for (int nt = 0; nt < 4; ++nt) {
    const int n = bn * 64 + nt * 16 + cl;
    const float bv = bias[n];
#pragma unroll
    for (int r = 0; r < 4; ++r) {
      const int m = bm * 64 + rbase + r;
      const float v = acc[nt][r] + bv;
      if (MODE == 0) {
        C[(size_t)m * N + n] = v;
      } else {
        const int t = m >> 6, bb = m & 63;
        if (t < T - 1) C[((size_t)(bb * (T - 1) + t)) * V + n] = v;
      }
    }
  }
}

// ---- persistent 3-role GRU pipeline ----------------------------------------
// 192 blocks x 256 threads (cooperative). role = bx>>6, jb = bx&63.
// Interval i: L1 computes h1[t=i] (i<512); GX computes gx2[t=i-1] (1<=i<=512);
// L2 computes h2[t=i-2] (2<=i<=513), whose sc1 ring write IS the y2 output.
// h1 ring slab s (mod 128) = h1 state entering step s; h2 ring slab s (full
// 513) = h2 state entering step s. Producers write slabs with sc1 (no dirty
// L2 line anywhere); consumers read with plain cached loads -- safe because
// each slab address is written exactly once before any consumer touches it.
__global__ __launch_bounds__(256, 1) void gru_persist(
    const f16* __restrict__ pW, const float* __restrict__ G0,
    const int* __restrict__ X, const float* __restrict__ b_hh,
    const float* __restrict__ b_ih, f16* __restrict__ h1ring,
    f16* __restrict__ h2ring, float* __restrict__ gx2, int* __restrict__ bar) {
  __shared__ __align__(16) f16 Wt[55296];  // [k0<32][row<48][kk padded to 36]

  const int tid = threadIdx.x, bx = blockIdx.x;
  const int lane = tid & 63, wv = tid >> 6;
  const int l15 = lane & 15, kq = lane >> 4;
  const int role = bx >> 6, jb = bx & 63;

  int* arrive = bar;
  int* door = bar + 4096;

  // ---- stage this block's 96KB W image (dense global -> padded LDS) ----
  {
    const int2* src = reinterpret_cast<const int2*>(pW + (size_t)bx * 49152);
#pragma unroll
    for (int q = 0; q < 48; ++q) {
      const int flat = q * 256 + tid;   // 12288 int2
      const int k0r = flat >> 3, seg = flat & 7;
      *reinterpret_cast<int2*>(&Wt[k0r * 36 + seg * 4]) = src[flat];
    }
  }
  __syncthreads();

  const int j = jb * 16 + l15;
  float br_ = 0.f, bz_ = 0.f, bn_ = 0.f, bxr_ = 0.f, bxz_ = 0.f, bxn_ = 0.f;
  if (role == 0) {
    br_ = b_hh[j]; bz_ = b_hh[H + j]; bn_ = b_hh[2 * H + j];
  } else if (role == 2) {
    br_ = b_hh[G + j]; bz_ = b_hh[G + H + j]; bn_ = b_hh[G + 2 * H + j];
    bxr_ = b_ih[G + j]; bxz_ = b_ih[G + H + j]; bxn_ = b_ih[G + 2 * H + j];
  }

  const int aoff = (wv * 16 + l15) * 32 + kq * 8;
  const f16* wp = Wt + l15 * 36 + kq * 8;  // + k0*1728 + g*576
  const int bB = wv * 16 + kq * 4;
  const size_t hoff = (size_t)(j >> 5) * 2048 + (j & 31);

  for (int i = 0; i <= T + 1; ++i) {
    if (role == 0) {
      if (i < T) {  // ---- L1: h1[t=i] : slab(i) -> slab(i+1) ----
        const f16* hin = h1ring + (size_t)(i & R1MASK) * SLAB;
        f16* hout = h1ring + (size_t)((i + 1) & R1MASK) * SLAB;
        f32x4 aR = {0, 0, 0, 0}, aZ = {0, 0, 0, 0}, aN = {0, 0, 0, 0};
        mm48(hin + aoff, wp, aR, aZ, aN);
#pragma unroll
        for (int r = 0; r < 4; ++r) {
          const int b = bB + r;
          const float* gx = G0 + (size_t)X[b * T + i] * G;
          const float xr = gx[j], xz = gx[H + j], xn = gx[2 * H + j];
          const size_t ha = hoff + (size_t)b * 32;
          const float hp = lload2(hin + ha);
          const float rg = 1.f / (1.f + __expf(-(xr + aR[r] + br_)));
          const float zg = 1.f / (1.f + __expf(-(xz + aZ[r] + bz_)));
          const float ng = tanhf(xn + rg * (aN[r] + bn_));
          astore2(hout + ha, (1.f - zg) * ng + zg * hp);
        }
      }
    } else if (role == 1) {
      if (i >= 1 && i <= T) {  // ---- GX: gx2[t=i-1] = y1[t] @ W_ih1^T ----
        const int t = i - 1;
        f32x4 aR = {0, 0, 0, 0}, aZ = {0, 0, 0, 0}, aN = {0, 0, 0, 0};
        // y1[t] = h1 state entering step i = slab(i)
        mm48(h1ring + (size_t)(i & R1MASK) * SLAB + aoff, wp, aR, aZ, aN);
        float* gdst = gx2 + ((size_t)(t & 1) * 64 + jb) * 3072;
#pragma unroll
        for (int r = 0; r < 4; ++r) {
          const int b = bB + r;
          astoref(gdst + b * 16 + l15, aR[r]);
          astoref(gdst + 1024 + b * 16 + l15, aZ[r]);
          astoref(gdst + 2048 + b * 16 + l15, aN[r]);
        }
      }
    } else {
      if (i >= 2) {  // ---- L2: h2[t=i-2] : slab(t) -> slab(t+1) (= y2[t]) ----
        const int t = i - 2;
        const f16* hin = h2ring + (size_t)t * SLAB;
        f16* hout = h2ring + (size_t)(t + 1) * SLAB;
        const float* gsrc = gx2 + ((size_t)(t & 1) * 64 + jb) * 3072;
        f32x4 aR = {0, 0, 0, 0}, aZ = {0, 0, 0, 0}, aN = {0, 0, 0, 0};
        mm48(hin + aoff, wp, aR, aZ, aN);
#pragma unroll
        for (int r = 0; r < 4; ++r) {
          const int b = bB + r;
          const float xr = aloadf(gsrc + b * 16 + l15);
          const float xz = aloadf(gsrc + 1024 + b * 16 + l15);
          const float xn = aloadf(gsrc + 2048 + b * 16 + l15);
          const size_t ha = hoff + (size_t)b * 32;
          const float hp = lload2(hin + ha);
          const float rg = 1.f / (1.f + __expf(-(xr + bxr_ + aR[r] + br_)));
          const float zg = 1.f / (1.f + __expf(-(xz + bxz_ + aZ[r] + bz_)));
          const float ng = tanhf(xn + bxn_ + rg * (aN[r] + bn_));
          const float hv = (1.f - zg) * ng + zg * hp;
          astore2(hout + ha, hv);  // sc1 ring write IS y2[t]
        }
      }
    }

    // ---- explicit publication drain + contention-free barrier (r11/r13) ----
    asm volatile("s_waitcnt vmcnt(0)" ::: "memory");
    __builtin_amdgcn_sched_barrier(0);
    __syncthreads();
    const int ph = i + 1;
    if (tid == 0) astorei(&arrive[bx * 16], ph);
    if (bx == 0) {
      if (tid < 64) {  // aggregator wave
        int a0, a1, a2;
        for (;;) {
          poll3(&arrive[tid * 16], &arrive[(64 + tid) * 16],
                &arrive[(128 + tid) * 16], a0, a1, a2);
          if (__all(a0 >= ph && a1 >= ph && a2 >= ph)) break;
          __builtin_amdgcn_s_sleep(1);
        }
        astorei(&door[tid * 16], ph);
        astorei(&door[(64 + tid) * 16], ph);
        astorei(&door[(128 + tid) * 16], ph);
      }
    } else if (tid == 0) {
      while (__hip_atomic_load(&door[bx * 16], __ATOMIC_RELAXED,
                               __HIP_MEMORY_SCOPE_AGENT) < ph) {
        __builtin_amdgcn_s_sleep(1);
      }
    }
    __syncthreads();
    asm volatile("" ::: "memory");
  }
}

}  // namespace

// ============================================================================
extern "C" void kernel_launch(void* const* d_in, const int* in_sizes, int n_in,
                              void* d_out, int out_size, void* d_ws,
                              size_t ws_size, hipStream_t stream) {
  const int* X = (const int*)d_in[0];
  const float* h0 = (const float*)d_in[1];
  const float* emb = (const float*)d_in[2];
  const float* W_ih = (const float*)d_in[3];
  const float* W_hh = (const float*)d_in[4];
  const float* b_ih = (const float*)d_in[5];
  const float* b_hh = (const float*)d_in[6];
  const float* W_out = (const float*)d_in[7];
  const float* b_out = (const float*)d_in[8];
  float* out = (float*)d_out;
  (void)in_sizes; (void)n_in; (void)out_size; (void)ws_size;

  // ---- workspace (~115 MB) ----
  char* p = (char*)d_ws;
  auto alloc = [&](size_t bytes) {
    char* q = p;
    p += (bytes + 255) & ~(size_t)255;
    return q;
  };
  f16* pW = (f16*)alloc((size_t)3 * 64 * 49152 * 2);   // 18 MB (3 role images)
  float* G0 = (float*)alloc((size_t)V * G * 4);        // 3 MB
  f16* emb16 = (f16*)alloc((size_t)V * H * 2);
  f16* wih0_16 = (f16*)alloc((size_t)G * H * 2);       // 6 MB
  f16* wout16 = (f16*)alloc((size_t)V * H * 2);
  f16* h1ring = (f16*)alloc((size_t)128 * 65536 * 2);  // 16.8 MB (depth-128)
  f16* h2ring = (f16*)alloc((size_t)513 * 65536 * 2);  // 67.2 MB (doubles as y2)
  float* gx2 = (float*)alloc((size_t)2 * 64 * 3072 * 4);  // 1.5 MB
  int* bar = (int*)alloc(32768);  // arrive[192*16] + door at +4096 ints
  // arrive/door slots zeroed by pack_h0f (kernel-end writeback publishes).

  // ---- one-time converts / packs / G0 ----
  to_f16_4<<<(V * H / 4 + 255) / 256, 256, 0, stream>>>(emb, emb16, V * H / 4);
  to_f16_4<<<(G * H / 4 + 255) / 256, 256, 0, stream>>>(W_ih, wih0_16,
                                                        G * H / 4);
  to_f16_4<<<(V * H / 4 + 255) / 256, 256, 0, stream>>>(W_out, wout16,
                                                        V * H / 4);
  pack_w<<<4608, 256, 0, stream>>>(W_hh, W_ih, pW);
  pack_h0f<<<512, 256, 0, stream>>>(h0, h1ring, h2ring, bar);
  gemm_f16<0><<<dim3(G / 64, V / 64), 256, 0, stream>>>(emb16, wih0_16, b_ih,
                                                        G0, V, G, H);

  // ---- persistent 3-role pipeline (cooperative: guarantees co-residency) ----
  {
    const f16* a0 = pW; const float* a1 = G0; const int* a2 = X;
    const float* a3 = b_hh; const float* a4 = b_ih;
    f16* a5 = h1ring; f16* a6 = h2ring; float* a7 = gx2; int* a8 = bar;
    void* args[] = {&a0, &a1, &a2, &a3, &a4, &a5, &a6, &a7, &a8};
    hipLaunchCooperativeKernel((const void*)gru_persist, dim3(NBLK), dim3(256),
                               args, 0, stream);
  }

  // ---- logits = y2 @ W_out^T + b_out; y2[t] = h2ring slab t+1 ----
  gemm_f16<2><<<dim3(V / 64, T), 256, 0, stream>>>(h2ring + 65536, wout16,
                                                   b_out, out, T * B, V, H);
}